// Round 1
// baseline (140.206 us; speedup 1.0000x reference)
//
#include <hip/hip_runtime.h>
#include <float.h>

// Problem constants (from reference setup_inputs)
#define NS   16384   // samples
#define K1   512     // d_in
#define F    256     // n_feat
#define NC   1000    // n_classes
#define SPB  32      // samples per block
#define NTHR 512     // 8 waves
#define NBLK (NS / SPB)

// f16 split-precision MFMA plan:
//   value = hi + lo, hi = f16(v), lo = f16(v - hi)  => 2^-22 relative capture.
//   A*B ~= Ah*Bh + Ah*Bl + Al*Bh  (ll term ~2^-22 rel, dropped).
//   Pre-scale x*8, W*16, means*16: keeps lo terms in f16-normal range and is
//   argmax-invariant (positive scales).
// MFMA 16x16x32 f16 layouts (HW-verified m89/m91/m120):
//   A[m][k]: m=lane&15, k=(lane>>4)*8+j   (8 f16 per lane, k-contiguous)
//   B[k][n]: n=lane&15, k=(lane>>4)*8+j
//   C/D:     col=lane&15, row=(lane>>4)*4+reg
// Tie-break: reference argmin takes FIRST min => lowest class index wins.

typedef _Float16 half8  __attribute__((ext_vector_type(8)));
typedef float    float4v __attribute__((ext_vector_type(4)));
typedef float    float2v __attribute__((ext_vector_type(2)));

// Workspace layout in halves (_Float16), TILE-INTERLEAVED hi/lo:
//   W region:  256 tiles (tile = ks*16+nt), each tile 1024 halves:
//              hi at tile*1024 + lane*8, lo at tile*1024 + 512 + lane*8
//   M region:  512 tiles (tile = ks*64+gt) at M_OFF, same intra-tile layout.
//   total = 262144 + 524288 = 786432 halves = 1.5 MB
#define M_OFF 262144

// ---- merged prep: W and means -> swizzled f16 hi/lo fragments (scale 16) ----
__global__ void prep(const float* __restrict__ W, const float* __restrict__ means,
                     _Float16* __restrict__ ws) {
    int g = blockIdx.x * blockDim.x + threadIdx.x;   // 0..49151
    if (g < 16384) {
        // W[512][256] fragments
        int lane = g & 63, tile = g >> 6;            // tile = ks*16+nt
        int ks = tile >> 4, nt = tile & 15;
        int k0 = ks * 32 + (lane >> 4) * 8;
        int n  = nt * 16 + (lane & 15);
        half8 hv, lv;
#pragma unroll
        for (int j = 0; j < 8; ++j) {
            float v = W[(size_t)(k0 + j) * F + n] * 16.0f;
            _Float16 hi = (_Float16)v;
            hv[j] = hi;
            lv[j] = (_Float16)(v - (float)hi);
        }
        _Float16* d = ws + (size_t)tile * 1024 + (size_t)lane * 8;
        *reinterpret_cast<half8*>(d)       = hv;
        *reinterpret_cast<half8*>(d + 512) = lv;
    } else {
        // means[1000][256] fragments, zero-pad c>=NC
        int gm = g - 16384;                          // 0..32767
        int lane = gm & 63, tile = gm >> 6;          // tile = ks*64+gt
        int ks = tile >> 6, gt = tile & 63;
        int k0 = ks * 32 + (lane >> 4) * 8;
        int c  = gt * 16 + (lane & 15);
        half8 hv, lv;
#pragma unroll
        for (int j = 0; j < 8; ++j) {
            float v = (c < NC) ? means[(size_t)c * F + k0 + j] * 16.0f : 0.0f;
            _Float16 hi = (_Float16)v;
            hv[j] = hi;
            lv[j] = (_Float16)(v - (float)hi);
        }
        _Float16* d = ws + M_OFF + (size_t)tile * 1024 + (size_t)lane * 8;
        *reinterpret_cast<half8*>(d)       = hv;
        *reinterpret_cast<half8*>(d + 512) = lv;
    }
}

#define MFMA(a, b, c) __builtin_amdgcn_mfma_f32_16x16x32_f16((a), (b), (c), 0, 0, 0)

__attribute__((amdgpu_flat_work_group_size(NTHR, NTHR), amdgpu_waves_per_eu(2, 4)))
__global__ void fused_mfma(const float* __restrict__ x,
                           const _Float16* __restrict__ ws,
                           float* __restrict__ out) {
    __shared__ _Float16 xsh[2][32][44];   // x chunk hi, ping-pong, padded stride
    __shared__ _Float16 xsl[2][32][44];   // x chunk lo
    __shared__ _Float16 fh[32][264];      // feats hi (scaled x128), padded stride
    __shared__ _Float16 fl[32][264];      // feats lo
    __shared__ float cand_v[32][8];
    __shared__ int   cand_i[32][8];
    __shared__ int   bidx[32];

    const int tid  = threadIdx.x;
    const int lane = tid & 63;
    const int w    = tid >> 6;    // wave 0..7
    const int quad = lane >> 4;   // 0..3
    const int cl   = lane & 15;
    const int s0   = blockIdx.x * SPB;

    // staging coords: 512 threads cover 32 rows x 32 cols (2 floats each)
    const int xrow = tid >> 4;          // 0..31
    const int xc   = (tid & 15) * 2;    // 0,2,..,30

    // ================= Phase 1: feats = (8x) @ (16W), f16-split MFMA ========
    float4v acc1[2][2];   // [p = n-subtile][mt]
#pragma unroll
    for (int p = 0; p < 2; ++p)
#pragma unroll
        for (int mt = 0; mt < 2; ++mt)
            acc1[p][mt] = (float4v){0.f, 0.f, 0.f, 0.f};

    // W-fragment register double-buffer: prefetch ks+1 while MFMAing ks
    const _Float16* wsrc = ws + ((size_t)(w * 2) << 10) + ((size_t)lane << 3);
    half8 wbh[2][2], wbl[2][2];
#pragma unroll
    for (int p = 0; p < 2; ++p) {
        wbh[0][p] = *reinterpret_cast<const half8*>(wsrc + p * 1024);
        wbl[0][p] = *reinterpret_cast<const half8*>(wsrc + p * 1024 + 512);
    }

    float2v xv = __builtin_nontemporal_load(
        reinterpret_cast<const float2v*>(x + (size_t)(s0 + xrow) * K1 + xc));

#pragma unroll
    for (int ks = 0; ks < 16; ++ks) {
        const int buf = ks & 1;
        {   // convert (scale x8) and stage
            float vx = xv.x * 8.0f, vy = xv.y * 8.0f;
            _Float16 hx = (_Float16)vx, hy = (_Float16)vy;
            xsh[buf][xrow][xc]     = hx;
            xsh[buf][xrow][xc + 1] = hy;
            xsl[buf][xrow][xc]     = (_Float16)(vx - (float)hx);
            xsl[buf][xrow][xc + 1] = (_Float16)(vy - (float)hy);
        }
        if (ks < 15)
            xv = __builtin_nontemporal_load(
                reinterpret_cast<const float2v*>(
                    x + (size_t)(s0 + xrow) * K1 + (ks + 1) * 32 + xc));
        __syncthreads();
        if (ks < 15) {   // prefetch next-ks W fragments across the MFMAs below
#pragma unroll
            for (int p = 0; p < 2; ++p) {
                wbh[buf ^ 1][p] = *reinterpret_cast<const half8*>(
                    wsrc + (size_t)(ks + 1) * 16384 + p * 1024);
                wbl[buf ^ 1][p] = *reinterpret_cast<const half8*>(
                    wsrc + (size_t)(ks + 1) * 16384 + p * 1024 + 512);
            }
        }
        half8 ah[2], al[2];
#pragma unroll
        for (int mt = 0; mt < 2; ++mt) {
            ah[mt] = *reinterpret_cast<const half8*>(&xsh[buf][mt * 16 + cl][quad * 8]);
            al[mt] = *reinterpret_cast<const half8*>(&xsl[buf][mt * 16 + cl][quad * 8]);
        }
#pragma unroll
        for (int p = 0; p < 2; ++p)
#pragma unroll
            for (int mt = 0; mt < 2; ++mt) {
                acc1[p][mt] = MFMA(ah[mt], wbh[buf][p], acc1[p][mt]);
                acc1[p][mt] = MFMA(ah[mt], wbl[buf][p], acc1[p][mt]);
                acc1[p][mt] = MFMA(al[mt], wbh[buf][p], acc1[p][mt]);
            }
        // no trailing barrier: next iter writes the other buffer
    }

    // park feats (scaled x128) into LDS as f16 hi/lo
#pragma unroll
    for (int p = 0; p < 2; ++p)
#pragma unroll
        for (int mt = 0; mt < 2; ++mt)
#pragma unroll
            for (int r = 0; r < 4; ++r) {
                int srow = mt * 16 + quad * 4 + r;
                int n    = (w * 2 + p) * 16 + cl;
                float v  = acc1[p][mt][r];
                _Float16 hi = (_Float16)v;
                fh[srow][n] = hi;
                fl[srow][n] = (_Float16)(v - (float)hi);
            }
    __syncthreads();

    // ========== Phase 2: scores = feats @ means.T, f16-split MFMA ==========
    // Wave w owns class tiles gt = w*8..w*8+7 (classes w*128..w*128+127).
    // Software pipeline: 32 batches of 2 tiles; register double-buffer for
    // means fragments (prefetch batch b+1 during batch b's 12 MFMAs) and for
    // the LDS A-fragments (prefetch ks+1 two batches early).
    float4v acc2[2][8];   // [mt][nt]
#pragma unroll
    for (int mt = 0; mt < 2; ++mt)
#pragma unroll
        for (int nt = 0; nt < 8; ++nt)
            acc2[mt][nt] = (float4v){0.f, 0.f, 0.f, 0.f};

    const _Float16* mbase = ws + M_OFF + ((size_t)(w * 8) << 10) + ((size_t)lane << 3);

    half8 mh[2][2], ml[2][2];       // [buf][tile-in-batch]
    half8 fah[2][2], fal[2][2];     // [ks&1][mt]
#pragma unroll
    for (int t = 0; t < 2; ++t) {   // prologue: batch 0 (ks=0, nt=0..1)
        mh[0][t] = *reinterpret_cast<const half8*>(mbase + t * 1024);
        ml[0][t] = *reinterpret_cast<const half8*>(mbase + t * 1024 + 512);
    }
#pragma unroll
    for (int mt = 0; mt < 2; ++mt) { // prologue: A-frags for ks=0
        fah[0][mt] = *reinterpret_cast<const half8*>(&fh[mt * 16 + cl][quad * 8]);
        fal[0][mt] = *reinterpret_cast<const half8*>(&fl[mt * 16 + cl][quad * 8]);
    }

#pragma unroll
    for (int b = 0; b < 32; ++b) {
        const int cb = b & 1;        // means-frag buffer holding batch b
        const int ks = b >> 2;
        const int ab = ks & 1;       // A-frag buffer for ks
        if (b < 31) {                // prefetch means frags for batch b+1
            const int b2 = b + 1;
            const _Float16* src =
                mbase + (size_t)((b2 >> 2) * 65536 + (b2 & 3) * 2048);
#pragma unroll
            for (int t = 0; t < 2; ++t) {
                mh[cb ^ 1][t] = *reinterpret_cast<const half8*>(src + t * 1024);
                ml[cb ^ 1][t] = *reinterpret_cast<const half8*>(src + t * 1024 + 512);
            }
        }
        if ((b & 3) == 2 && ks < 7) { // prefetch A-frags for ks+1
#pragma unroll
            for (int mt = 0; mt < 2; ++mt) {
                fah[ab ^ 1][mt] = *reinterpret_cast<const half8*>(
                    &fh[mt * 16 + cl][(ks + 1) * 32 + quad * 8]);
                fal[ab ^ 1][mt] = *reinterpret_cast<const half8*>(
                    &fl[mt * 16 + cl][(ks + 1) * 32 + quad * 8]);
            }
        }
        const int n0 = (b & 3) * 2;
#pragma unroll
        for (int t = 0; t < 2; ++t) {
            const int nt = n0 + t;
#pragma unroll
            for (int mt = 0; mt < 2; ++mt) {
                acc2[mt][nt] = MFMA(fah[ab][mt], mh[cb][t], acc2[mt][nt]);
                acc2[mt][nt] = MFMA(fah[ab][mt], ml[cb][t], acc2[mt][nt]);
                acc2[mt][nt] = MFMA(fal[ab][mt], mh[cb][t], acc2[mt][nt]);
            }
        }
    }

    // ---- argmax from C/D layout: row=quad*4+r, col=cl ----
#pragma unroll
    for (int mt = 0; mt < 2; ++mt)
#pragma unroll
        for (int r = 0; r < 4; ++r) {
            float v  = -FLT_MAX;
            int   ix = 0x7FFFFFFF;
#pragma unroll
            for (int nt = 0; nt < 8; ++nt) {          // ascending class order
                int c = (w * 8 + nt) * 16 + cl;
                if (c < NC) {
                    float sc = acc2[mt][nt][r];
                    if (sc > v) { v = sc; ix = c; }   // strict >: lowest wins
                }
            }
            // merge across the 16 lanes of this quad (they hold cl=0..15)
#pragma unroll
            for (int off = 1; off < 16; off <<= 1) {
                float ov = __shfl_xor(v, off, 64);
                int   oi = __shfl_xor(ix, off, 64);
                if (ov > v || (ov == v && oi < ix)) { v = ov; ix = oi; }
            }
            if (cl == 0) {
                int srow = mt * 16 + quad * 4 + r;
                cand_v[srow][w] = v;
                cand_i[srow][w] = ix;
            }
        }
    __syncthreads();

    if (tid < 32) {   // merge the 8 wave-candidates, ascending class ranges
        float v  = cand_v[tid][0];
        int   ix = cand_i[tid][0];
#pragma unroll
        for (int q = 1; q < 8; ++q) {
            float ov = cand_v[tid][q];
            int   oi = cand_i[tid][q];
            if (ov > v || (ov == v && oi < ix)) { v = ov; ix = oi; }
        }
        bidx[tid] = ix;
    }
    __syncthreads();

    // ================= Epilogue: write one-hot rows (nontemporal) =========
    const int NF4 = NC / 4;  // 250 float4 per row
    for (int q = tid; q < SPB * NF4; q += NTHR) {
        int row   = q / NF4;
        int c4    = q - row * NF4;
        int b     = bidx[row];
        int cbase = c4 * 4;
        float4v v;
        v.x = (cbase + 0 == b) ? 1.f : 0.f;
        v.y = (cbase + 1 == b) ? 1.f : 0.f;
        v.z = (cbase + 2 == b) ? 1.f : 0.f;
        v.w = (cbase + 3 == b) ? 1.f : 0.f;
        __builtin_nontemporal_store(
            v, reinterpret_cast<float4v*>(out + (size_t)(s0 + row) * NC + cbase));
    }
}

extern "C" void kernel_launch(void* const* d_in, const int* in_sizes, int n_in,
                              void* d_out, int out_size, void* d_ws, size_t ws_size,
                              hipStream_t stream) {
    const float* x     = (const float*)d_in[0];
    const float* W     = (const float*)d_in[1];
    const float* means = (const float*)d_in[2];
    float* out         = (float*)d_out;
    _Float16* ws       = (_Float16*)d_ws;   // 1.5 MB of swizzled f16 fragments

    prep<<<192, 256, 0, stream>>>(W, means, ws);
    fused_mfma<<<NBLK, NTHR, 0, stream>>>(x, ws, out);
}

// Round 2
// 132.088 us; speedup vs baseline: 1.0615x; 1.0615x over previous
//
#include <hip/hip_runtime.h>
#include <float.h>

// Problem constants (from reference setup_inputs)
#define NS   16384   // samples
#define K1   512     // d_in
#define F    256     // n_feat
#define NC   1000    // n_classes
#define SPB  64      // samples per block (doubled: halves means L2 traffic)
#define NTHR 512     // 8 waves
#define NBLK (NS / SPB)   // 256 blocks = exactly 1 per CU

// f16 split-precision MFMA plan:
//   value = hi + lo, hi = f16(v), lo = f16(v - hi)  => 2^-22 relative capture.
//   A*B ~= Ah*Bh + Ah*Bl + Al*Bh  (ll term ~2^-22 rel, dropped).
//   Pre-scale x*8, W*16, means*16: keeps lo terms in f16-normal range and is
//   argmax-invariant (positive scales).
// MFMA 16x16x32 f16 layouts (HW-verified m89/m91/m120):
//   A[m][k]: m=lane&15, k=(lane>>4)*8+j   (8 f16 per lane, k-contiguous)
//   B[k][n]: n=lane&15, k=(lane>>4)*8+j
//   C/D:     col=lane&15, row=(lane>>4)*4+reg
// Tie-break: reference argmin takes FIRST min => lowest class index wins.

typedef _Float16 half8  __attribute__((ext_vector_type(8)));
typedef float    float4v __attribute__((ext_vector_type(4)));

// Workspace layout in halves (_Float16), TILE-INTERLEAVED hi/lo:
//   W region:  256 tiles (tile = ks*16+nt), each tile 1024 halves:
//              hi at tile*1024 + lane*8, lo at tile*1024 + 512 + lane*8
//   M region:  512 tiles (tile = ks*64+gt) at M_OFF, same intra-tile layout.
#define M_OFF 262144

// ---- merged prep: W and means -> swizzled f16 hi/lo fragments (scale 16) ----
__global__ void prep(const float* __restrict__ W, const float* __restrict__ means,
                     _Float16* __restrict__ ws) {
    int g = blockIdx.x * blockDim.x + threadIdx.x;   // 0..49151
    if (g < 16384) {
        int lane = g & 63, tile = g >> 6;            // tile = ks*16+nt
        int ks = tile >> 4, nt = tile & 15;
        int k0 = ks * 32 + (lane >> 4) * 8;
        int n  = nt * 16 + (lane & 15);
        half8 hv, lv;
#pragma unroll
        for (int j = 0; j < 8; ++j) {
            float v = W[(size_t)(k0 + j) * F + n] * 16.0f;
            _Float16 hi = (_Float16)v;
            hv[j] = hi;
            lv[j] = (_Float16)(v - (float)hi);
        }
        _Float16* d = ws + (size_t)tile * 1024 + (size_t)lane * 8;
        *reinterpret_cast<half8*>(d)       = hv;
        *reinterpret_cast<half8*>(d + 512) = lv;
    } else {
        int gm = g - 16384;                          // 0..32767
        int lane = gm & 63, tile = gm >> 6;          // tile = ks*64+gt
        int ks = tile >> 6, gt = tile & 63;
        int k0 = ks * 32 + (lane >> 4) * 8;
        int c  = gt * 16 + (lane & 15);
        half8 hv, lv;
#pragma unroll
        for (int j = 0; j < 8; ++j) {
            float v = (c < NC) ? means[(size_t)c * F + k0 + j] * 16.0f : 0.0f;
            _Float16 hi = (_Float16)v;
            hv[j] = hi;
            lv[j] = (_Float16)(v - (float)hi);
        }
        _Float16* d = ws + M_OFF + (size_t)tile * 1024 + (size_t)lane * 8;
        *reinterpret_cast<half8*>(d)       = hv;
        *reinterpret_cast<half8*>(d + 512) = lv;
    }
}

#define MFMA(a, b, c) __builtin_amdgcn_mfma_f32_16x16x32_f16((a), (b), (c), 0, 0, 0)

__attribute__((amdgpu_flat_work_group_size(NTHR, NTHR), amdgpu_waves_per_eu(2, 4)))
__global__ void fused_mfma(const float* __restrict__ x,
                           const _Float16* __restrict__ ws,
                           float* __restrict__ out) {
    // LDS ~92 KB -> 1 block/CU, 8 waves (2/SIMD). Deliberate: 2x work per
    // wave, means traffic halved, deep register pipelining supplies ILP.
    __shared__ _Float16 xsh[2][64][40];   // x chunk hi, ping-pong, padded stride
    __shared__ _Float16 xsl[2][64][40];   // x chunk lo
    __shared__ _Float16 fh[64][264];      // feats hi (scaled x128), padded stride
    __shared__ _Float16 fl[64][264];      // feats lo
    __shared__ float cand_v[64][8];
    __shared__ int   cand_i[64][8];
    __shared__ int   bidx[64];

    const int tid  = threadIdx.x;
    const int lane = tid & 63;
    const int w    = tid >> 6;    // wave 0..7
    const int quad = lane >> 4;   // 0..3
    const int cl   = lane & 15;
    const int s0   = blockIdx.x * SPB;

    // staging coords: 512 threads cover 64 rows x 32 cols (float4 each)
    const int xrow = tid >> 3;          // 0..63
    const int xc4  = (tid & 7) * 4;     // 0,4,..,28

    // ================= Phase 1: feats = (8x) @ (16W), f16-split MFMA ========
    float4v acc1[2][4];   // [p = n-subtile][mt]
#pragma unroll
    for (int p = 0; p < 2; ++p)
#pragma unroll
        for (int mt = 0; mt < 4; ++mt)
            acc1[p][mt] = (float4v){0.f, 0.f, 0.f, 0.f};

    // W-fragment register double-buffer: prefetch ks+1 while MFMAing ks
    const _Float16* wsrc = ws + ((size_t)(w * 2) << 10) + ((size_t)lane << 3);
    half8 wbh[2][2], wbl[2][2];
#pragma unroll
    for (int p = 0; p < 2; ++p) {
        wbh[0][p] = *reinterpret_cast<const half8*>(wsrc + p * 1024);
        wbl[0][p] = *reinterpret_cast<const half8*>(wsrc + p * 1024 + 512);
    }

    float4v xv = __builtin_nontemporal_load(
        reinterpret_cast<const float4v*>(x + (size_t)(s0 + xrow) * K1 + xc4));

#pragma unroll
    for (int ks = 0; ks < 16; ++ks) {
        const int buf = ks & 1;
        {   // convert (scale x8) and stage 4 values
#pragma unroll
            for (int j = 0; j < 4; ++j) {
                float v = xv[j] * 8.0f;
                _Float16 hi = (_Float16)v;
                xsh[buf][xrow][xc4 + j] = hi;
                xsl[buf][xrow][xc4 + j] = (_Float16)(v - (float)hi);
            }
        }
        if (ks < 15)
            xv = __builtin_nontemporal_load(
                reinterpret_cast<const float4v*>(
                    x + (size_t)(s0 + xrow) * K1 + (ks + 1) * 32 + xc4));
        __syncthreads();
        if (ks < 15) {   // prefetch next-ks W fragments across the MFMAs below
#pragma unroll
            for (int p = 0; p < 2; ++p) {
                wbh[buf ^ 1][p] = *reinterpret_cast<const half8*>(
                    wsrc + (size_t)(ks + 1) * 16384 + p * 1024);
                wbl[buf ^ 1][p] = *reinterpret_cast<const half8*>(
                    wsrc + (size_t)(ks + 1) * 16384 + p * 1024 + 512);
            }
        }
        half8 ah[4], al[4];
#pragma unroll
        for (int mt = 0; mt < 4; ++mt) {
            ah[mt] = *reinterpret_cast<const half8*>(&xsh[buf][mt * 16 + cl][quad * 8]);
            al[mt] = *reinterpret_cast<const half8*>(&xsl[buf][mt * 16 + cl][quad * 8]);
        }
#pragma unroll
        for (int p = 0; p < 2; ++p)
#pragma unroll
            for (int mt = 0; mt < 4; ++mt) {
                acc1[p][mt] = MFMA(ah[mt], wbh[buf][p], acc1[p][mt]);
                acc1[p][mt] = MFMA(ah[mt], wbl[buf][p], acc1[p][mt]);
                acc1[p][mt] = MFMA(al[mt], wbh[buf][p], acc1[p][mt]);
            }
        // no trailing barrier: next iter writes the other buffer
    }

    // park feats (scaled x128) into LDS as f16 hi/lo
#pragma unroll
    for (int p = 0; p < 2; ++p)
#pragma unroll
        for (int mt = 0; mt < 4; ++mt)
#pragma unroll
            for (int r = 0; r < 4; ++r) {
                int srow = mt * 16 + quad * 4 + r;
                int n    = (w * 2 + p) * 16 + cl;
                float v  = acc1[p][mt][r];
                _Float16 hi = (_Float16)v;
                fh[srow][n] = hi;
                fl[srow][n] = (_Float16)(v - (float)hi);
            }
    __syncthreads();

    // ========== Phase 2: scores = feats @ means.T, f16-split MFMA ==========
    // Wave w owns class tiles gt = w*8..w*8+7 (classes w*128..w*128+127) for
    // all 4 M-tiles => each B-frag load feeds 12 MFMAs. Register dbuf for
    // means fragments (prefetch tile ii+1 during tile ii's 12 MFMAs).
    // One-hot zero-writes are PACED through this loop (4 float4/thread/ks):
    // drain (~0.24us/ks) hides under ~1.5us of MFMA per ks, converting the
    // 64MB output write from a 10us serial tail into background writeback.
    float4v acc2[4][8];   // [mt][gt]
#pragma unroll
    for (int mt = 0; mt < 4; ++mt)
#pragma unroll
        for (int gt = 0; gt < 8; ++gt)
            acc2[mt][gt] = (float4v){0.f, 0.f, 0.f, 0.f};

    const _Float16* mbase = ws + M_OFF + ((size_t)(w * 8) << 10) + ((size_t)lane << 3);

    half8 mh[2], ml[2];
    mh[0] = *reinterpret_cast<const half8*>(mbase);
    ml[0] = *reinterpret_cast<const half8*>(mbase + 512);

    const float4v z4 = (float4v){0.f, 0.f, 0.f, 0.f};
    const int NF4 = NC / 4;  // 250 float4 per row

#pragma unroll
    for (int ks = 0; ks < 8; ++ks) {
        half8 fah[4], fal[4];
#pragma unroll
        for (int mt = 0; mt < 4; ++mt) {
            fah[mt] = *reinterpret_cast<const half8*>(
                &fh[mt * 16 + cl][ks * 32 + quad * 8]);
            fal[mt] = *reinterpret_cast<const half8*>(
                &fl[mt * 16 + cl][ks * 32 + quad * 8]);
        }
        // paced one-hot zero stores (8 ks * 4 * 512thr * 4fl = 65536 >= 64000)
#pragma unroll
        for (int j = 0; j < 4; ++j) {
            int q = (ks * 4 + j) * NTHR + tid;
            if (q < SPB * NF4) {
                int row = q / NF4;
                int c4  = q - row * NF4;
                __builtin_nontemporal_store(
                    z4, reinterpret_cast<float4v*>(
                            out + (size_t)(s0 + row) * NC + c4 * 4));
            }
        }
#pragma unroll
        for (int gt = 0; gt < 8; ++gt) {
            const int ii = ks * 8 + gt;
            const int cb = ii & 1;
            if (ii < 63) {   // prefetch next means tile
                const _Float16* src = mbase +
                    (size_t)(((ii + 1) >> 3) * 65536 + ((ii + 1) & 7) * 1024);
                mh[cb ^ 1] = *reinterpret_cast<const half8*>(src);
                ml[cb ^ 1] = *reinterpret_cast<const half8*>(src + 512);
            }
#pragma unroll
            for (int mt = 0; mt < 4; ++mt) {
                acc2[mt][gt] = MFMA(fah[mt], mh[cb], acc2[mt][gt]);
                acc2[mt][gt] = MFMA(fah[mt], ml[cb], acc2[mt][gt]);
                acc2[mt][gt] = MFMA(fal[mt], mh[cb], acc2[mt][gt]);
            }
        }
    }

    // ---- argmax from C/D layout: row=quad*4+r, col=cl ----
#pragma unroll
    for (int mt = 0; mt < 4; ++mt)
#pragma unroll
        for (int r = 0; r < 4; ++r) {
            float v  = -FLT_MAX;
            int   ix = 0x7FFFFFFF;
#pragma unroll
            for (int nt = 0; nt < 8; ++nt) {          // ascending class order
                int c = (w * 8 + nt) * 16 + cl;
                if (c < NC) {
                    float sc = acc2[mt][nt][r];
                    if (sc > v) { v = sc; ix = c; }   // strict >: lowest wins
                }
            }
            // merge across the 16 lanes of this quad (they hold cl=0..15)
#pragma unroll
            for (int off = 1; off < 16; off <<= 1) {
                float ov = __shfl_xor(v, off, 64);
                int   oi = __shfl_xor(ix, off, 64);
                if (ov > v || (ov == v && oi < ix)) { v = ov; ix = oi; }
            }
            if (cl == 0) {
                int srow = mt * 16 + quad * 4 + r;
                cand_v[srow][w] = v;
                cand_i[srow][w] = ix;
            }
        }
    __syncthreads();

    if (tid < SPB) {   // merge the 8 wave-candidates, ascending class ranges
        float v  = cand_v[tid][0];
        int   ix = cand_i[tid][0];
#pragma unroll
        for (int q = 1; q < 8; ++q) {
            float ov = cand_v[tid][q];
            int   oi = cand_i[tid][q];
            if (ov > v || (ov == v && oi < ix)) { v = ov; ix = oi; }
        }
        bidx[tid] = ix;
    }
    __syncthreads();   // also orders: all zero-stores drained before the 1-writes

    // ================= Epilogue: single 1.0 per row =================
    if (tid < SPB)
        out[(size_t)(s0 + tid) * NC + bidx[tid]] = 1.0f;
}

extern "C" void kernel_launch(void* const* d_in, const int* in_sizes, int n_in,
                              void* d_out, int out_size, void* d_ws, size_t ws_size,
                              hipStream_t stream) {
    const float* x     = (const float*)d_in[0];
    const float* W     = (const float*)d_in[1];
    const float* means = (const float*)d_in[2];
    float* out         = (float*)d_out;
    _Float16* ws       = (_Float16*)d_ws;   // 1.5 MB of swizzled f16 fragments

    prep<<<192, 256, 0, stream>>>(W, means, ws);
    fused_mfma<<<NBLK, NTHR, 0, stream>>>(x, ws, out);
}